// Round 9
// baseline (253.518 us; speedup 1.0000x reference)
//
#include <hip/hip_runtime.h>
#include <hip/hip_bf16.h>
#include <cstdint>

// ---------------------------------------------------------------------------
// SingleHeadAttentionLayer: B=4, S=2048, D=KD=VD=1024, fp32 in/out.
// Round 9: algebraic elimination of the k-projection (softmax needs no max
// subtraction, so scores enter only as q.k^T):
//   q_i.k_j = x_i (Wq^T Wk) x_j^T + x_i.(Wq^T bk) + (Wk^T bq).x_j + bq.bk
// Precompute M=(Wk^T)(Wq^T)^T, w1=Wq^T bk, w2=Wk^T bq, c=bq.bk. Then
//   y = x@M^T + w2              (replaces BOTH q and k projections)
//   scores = y@x^T + r1_i,  r1 = x@w1 + c
//   U  = x@Wvo^T + bvo  (round-5 algebra: Wvo=Wo@Wv, bvo=bv@Wo^T)
//   P  = exp(|scores|/32) causal + atomic rowsums
//   out = (P@U)/l + bo
// Dispatches: prep | wcomb(145) | proj(1088: y+U+r1) | scores(544) | pvo(512)
// ---------------------------------------------------------------------------

#define BM 128

typedef __attribute__((ext_vector_type(8))) __bf16 bf16x8;
typedef __attribute__((ext_vector_type(4))) __bf16 bf16x4;
typedef __attribute__((ext_vector_type(4))) float floatx4;

__device__ __forceinline__ void async_copy16(const __bf16* g, const __bf16* l) {
  __builtin_amdgcn_global_load_lds(
      (const __attribute__((address_space(1))) unsigned int*)(const void*)g,
      (__attribute__((address_space(3))) unsigned int*)(unsigned)(uintptr_t)(const void*)l,
      16, 0, 0);
}

// 128x128 tile; K consumed 64/iter as two 32-panels (verified lane-linear
// global_load_lds layout, free 2-way bank pattern). Iterates [kBeg, kEnd).
// ONE call site per kernel (single 32 KB LDS instance).
__device__ __forceinline__ void gemm_core(const __bf16* __restrict__ pA,
                                          const __bf16* __restrict__ pB,
                                          int K, int kBeg, int kEnd, int mb,
                                          int nb, floatx4 (&acc)[4][4]) {
  __shared__ __align__(16) __bf16 As0[BM * 32];
  __shared__ __align__(16) __bf16 As1[BM * 32];
  __shared__ __align__(16) __bf16 Bs0[BM * 32];
  __shared__ __align__(16) __bf16 Bs1[BM * 32];

  const int t = threadIdx.x;
  const int lane = t & 63;
  const int wave = t >> 6;
  const int quad = lane >> 4;
  const int l16 = lane & 15;
  const int wm = wave >> 1;
  const int wn = wave & 1;

  const __bf16* gA = pA + (long)(mb * BM + (t >> 2)) * K + ((t & 3) * 8);
  const __bf16* gB = pB + (long)(nb * BM + (t >> 2)) * K + ((t & 3) * 8);
  const long rowHalf = (long)64 * K;
  __bf16* lA0 = &As0[t * 8];
  __bf16* lA1 = &As1[t * 8];
  __bf16* lB0 = &Bs0[t * 8];
  __bf16* lB1 = &Bs1[t * 8];

  for (int kk = kBeg; kk < kEnd; ++kk) {
    const long ko = (long)kk * 64;
    async_copy16(gA + ko, lA0);
    async_copy16(gA + ko + rowHalf, lA0 + 2048);
    async_copy16(gA + ko + 32, lA1);
    async_copy16(gA + ko + 32 + rowHalf, lA1 + 2048);
    async_copy16(gB + ko, lB0);
    async_copy16(gB + ko + rowHalf, lB0 + 2048);
    async_copy16(gB + ko + 32, lB1);
    async_copy16(gB + ko + 32 + rowHalf, lB1 + 2048);
    __syncthreads();

#pragma unroll
    for (int p = 0; p < 2; ++p) {
      const __bf16* As = p ? As1 : As0;
      const __bf16* Bs = p ? Bs1 : Bs0;
      bf16x8 af[4], bfr[4];
#pragma unroll
      for (int i = 0; i < 4; ++i) {
        af[i] = *(const bf16x8*)&As[(wm * 64 + i * 16 + l16) * 32 + quad * 8];
        bfr[i] = *(const bf16x8*)&Bs[(wn * 64 + i * 16 + l16) * 32 + quad * 8];
      }
#pragma unroll
      for (int i = 0; i < 4; ++i)
#pragma unroll
        for (int j = 0; j < 4; ++j)
          acc[i][j] = __builtin_amdgcn_mfma_f32_16x16x32_bf16(af[i], bfr[j],
                                                              acc[i][j], 0, 0, 0);
    }
    __syncthreads();
  }
}

// wave-wide fp32 sum (all 64 lanes get the result)
__device__ __forceinline__ float wave_sum(float s) {
  s += __shfl_xor(s, 1, 64);
  s += __shfl_xor(s, 2, 64);
  s += __shfl_xor(s, 4, 64);
  s += __shfl_xor(s, 8, 64);
  s += __shfl_xor(s, 16, 64);
  s += __shfl_xor(s, 32, 64);
  return s;
}

// ---------------- wcomb: M(64) + Wvo(64) GEMMs, w1(8), w2(8), c(1) ----------
__global__ void __launch_bounds__(256, 2)
wcomb(const __bf16* __restrict__ Wqt, const __bf16* __restrict__ Wkt,
      const __bf16* __restrict__ Wob, const __bf16* __restrict__ Wvt,
      __bf16* __restrict__ Mqk, __bf16* __restrict__ Wvo,
      const float* __restrict__ bq, const float* __restrict__ bk,
      float* __restrict__ w1, float* __restrict__ w2, float* __restrict__ cbuf) {
  const int id = blockIdx.x;
  const int t = threadIdx.x;

  if (id < 128) {
    // M[d2][d1] = Wkt[d2] . Wqt[d1]   (so y = gemm_bt(x, M) gives y.x^T = q.k^T)
    // Wvo[d][din] = Wob[d] . Wvt[din]
    const bool isM = id < 64;
    const int wid = isM ? id : (id - 64);
    const int mb = wid >> 3, nb = wid & 7;
    const __bf16* pA = isM ? Wkt : Wob;
    const __bf16* pB = isM ? Wqt : Wvt;
    __bf16* C = isM ? Mqk : Wvo;

    floatx4 acc[4][4] = {};
    gemm_core(pA, pB, 1024, 0, 16, mb, nb, acc);

    const int lane = t & 63, wave = t >> 6;
    const int rb = (wave >> 1) * 64 + (lane >> 4) * 4;
    const int cb = (wave & 1) * 64 + (lane & 15);
#pragma unroll
    for (int j4 = 0; j4 < 4; ++j4) {
      const int gc = nb * 128 + cb + j4 * 16;
#pragma unroll
      for (int i = 0; i < 4; ++i) {
        const int gr = mb * BM + rb + i * 16;
#pragma unroll
        for (int r = 0; r < 4; ++r)
          C[(long)(gr + r) * 1024 + gc] = (__bf16)acc[i][j4][r];
      }
    }
  } else if (id < 144) {
    // w1[d] = Wqt[d].bk   (8 jobs) ; w2[d] = Wkt[d].bq (8 jobs); 128 rows each
    const bool is1 = id < 136;
    const int jb = is1 ? (id - 128) : (id - 136);
    const __bf16* Wt = is1 ? Wqt : Wkt;
    const float* bb = is1 ? bk : bq;
    float* ow = is1 ? w1 : w2;
    const int lane = t & 63, wave = t >> 6;
    for (int rr = 0; rr < 32; ++rr) {
      const int row = jb * 128 + wave * 32 + rr;
      const bf16x8 a0 = *(const bf16x8*)&Wt[(long)row * 1024 + lane * 16];
      const bf16x8 a1 = *(const bf16x8*)&Wt[(long)row * 1024 + lane * 16 + 8];
      float s = 0.f;
#pragma unroll
      for (int e = 0; e < 8; ++e) {
        s += (float)a0[e] * bb[lane * 16 + e];
        s += (float)a1[e] * bb[lane * 16 + 8 + e];
      }
      s = wave_sum(s);
      if (lane == 0) ow[row] = s;
    }
  } else {
    // c = bq . bk
    __shared__ float wsum[4];
    float s = 0.f;
    for (int i = t; i < 1024; i += 256) s += bq[i] * bk[i];
    s = wave_sum(s);
    if ((t & 63) == 0) wsum[t >> 6] = s;
    __syncthreads();
    if (t == 0) cbuf[0] = wsum[0] + wsum[1] + wsum[2] + wsum[3];
  }
}

// ---------------- proj: y(512) + U(512) + r1(64) ----------------------------
__global__ void __launch_bounds__(256, 2)
proj(const __bf16* __restrict__ xb, const __bf16* __restrict__ Mqk,
     const __bf16* __restrict__ Wvo, const float* __restrict__ w2,
     const float* __restrict__ bvo, const float* __restrict__ w1,
     const float* __restrict__ cbuf, __bf16* __restrict__ yb,
     __bf16* __restrict__ Ut, float* __restrict__ r1, int S, int D) {
  const int id = blockIdx.x;
  const int t = threadIdx.x;

  if (id < 1024) {
    const bool isY = id < 512;
    const int pid = isY ? id : (id - 512);
    const int xcd = pid & 7;
    const int j = pid >> 3;       // 64 per XCD
    const int mb = xcd * 8 + (j & 7);
    const int nb = j >> 3;
    const __bf16* pB = isY ? Mqk : Wvo;

    floatx4 acc[4][4] = {};
    gemm_core(xb, pB, D, 0, D / 64, mb, nb, acc);

    const int lane = t & 63, wave = t >> 6;
    const int rb = (wave >> 1) * 64 + (lane >> 4) * 4;
    const int cb = (wave & 1) * 64 + (lane & 15);

    if (isY) {  // y = x@M^T + w2 (w2 bias absorbs the r2_j score term)
#pragma unroll
      for (int j4 = 0; j4 < 4; ++j4) {
        const int gc = nb * 128 + cb + j4 * 16;
        const float bv = w2[gc];
#pragma unroll
        for (int i = 0; i < 4; ++i) {
          const int gr = mb * BM + rb + i * 16;
#pragma unroll
          for (int r = 0; r < 4; ++r)
            yb[(long)(gr + r) * D + gc] = (__bf16)(acc[i][j4][r] + bv);
        }
      }
    } else {  // Ut[bb][dout][s] = U[bb][s][dout]
      const int bb = (mb * BM) / S;
      const int s0 = mb * BM - bb * S;
#pragma unroll
      for (int j4 = 0; j4 < 4; ++j4) {
        const int gc = nb * 128 + cb + j4 * 16;
        const float bv = bvo[gc];
#pragma unroll
        for (int i = 0; i < 4; ++i) {
          const int sr = s0 + rb + i * 16;
          bf16x4 o;
#pragma unroll
          for (int r = 0; r < 4; ++r) o[r] = (__bf16)(acc[i][j4][r] + bv);
          *(bf16x4*)&Ut[((long)bb * D + gc) * S + sr] = o;
        }
      }
    }
  } else {
    // r1[row] = xb[row].w1 + c   (64 jobs x 128 rows)
    const int jb = id - 1024;
    const float c = cbuf[0];
    const int lane = t & 63, wave = t >> 6;
    for (int rr = 0; rr < 32; ++rr) {
      const int row = jb * 128 + wave * 32 + rr;
      const bf16x8 a0 = *(const bf16x8*)&xb[(long)row * D + lane * 16];
      const bf16x8 a1 = *(const bf16x8*)&xb[(long)row * D + lane * 16 + 8];
      float s = 0.f;
#pragma unroll
      for (int e = 0; e < 8; ++e) {
        s += (float)a0[e] * w1[lane * 16 + e];
        s += (float)a1[e] * w1[lane * 16 + 8 + e];
      }
      s = wave_sum(s);
      if (lane == 0) r1[row] = s + c;
    }
  }
}

// ---------------- scores: P = exp(|y@x^T + r1|/32) causal + rowsums ---------
// 544 blocks, exact-packed: 17 uniform tiles per (XCD, batch), pair {x,15-x}.
__global__ void __launch_bounds__(256, 2)
gemm_scores(const __bf16* __restrict__ yb, const __bf16* __restrict__ xb,
            const float* __restrict__ r1, __bf16* __restrict__ P,
            float* __restrict__ lsum, int S, int D) {
  const int id = blockIdx.x;
  const int xcd = id & 7;
  const int r = id >> 3;          // 0..67
  const int b = r / 17;
  const int ci = r - b * 17;      // 0..16
  const int n1 = xcd + 1;
  const int mb = (ci < n1) ? xcd : (15 - xcd);
  const int nb = (ci < n1) ? ci : (ci - n1);

  floatx4 acc[4][4] = {};
  gemm_core(yb + (long)b * S * D, xb + (long)b * S * D, D, 0, D / 64, mb, nb,
            acc);

  const int t = threadIdx.x;
  const int lane = t & 63, wave = t >> 6;
  const int l16 = lane & 15;
  const int rb = (wave >> 1) * 64 + (lane >> 4) * 4;
  const int cb = (wave & 1) * 64 + l16;
  __bf16* C = P + (long)b * S * S;
  float* lrow = lsum + (long)b * S;
  const float* r1b = r1 + (long)b * S;
  const float sc = 0.03125f;  // 1/sqrt(1024)

#pragma unroll
  for (int i = 0; i < 4; ++i) {
#pragma unroll
    for (int r_ = 0; r_ < 4; ++r_) {
      const int row = mb * BM + rb + i * 16 + r_;
      const float rv = r1b[row];
      float psum = 0.f;
#pragma unroll
      for (int j4 = 0; j4 < 4; ++j4) {
        const int col = nb * 128 + cb + j4 * 16;
        const float p =
            (col <= row) ? __expf(fabsf((acc[i][j4][r_] + rv) * sc)) : 0.f;
        psum += p;
        C[(long)row * S + col] = (__bf16)p;
      }
      psum += __shfl_xor(psum, 1, 64);
      psum += __shfl_xor(psum, 2, 64);
      psum += __shfl_xor(psum, 4, 64);
      psum += __shfl_xor(psum, 8, 64);
      if (l16 == 0) atomicAdd(&lrow[row], psum);
    }
  }
}

// ---------------- pvo: out = (P @ U)/l + bo, fp32 ---------------------------
// 512 blocks; per XCD x: first half mb=15-x (heavy), second mb=x (light).
__global__ void __launch_bounds__(256, 2)
gemm_pvo(const __bf16* __restrict__ P, const __bf16* __restrict__ Ut,
         const float* __restrict__ lsum, const float* __restrict__ bo,
         float* __restrict__ out, int S, int D) {
  const int id = blockIdx.x;
  const int xcd = id & 7;
  const int j = id >> 3;          // 0..63
  const int half = j >> 5;
  const int idx = j & 31;
  const int b = idx >> 3;
  const int nb = idx & 7;
  const int mb = half ? xcd : (15 - xcd);

  floatx4 acc[4][4] = {};
  gemm_core(P + (long)b * S * S, Ut + (long)b * D * S, S, 0, 2 * (mb + 1), mb,
            nb, acc);

  const int t = threadIdx.x;
  const int lane = t & 63, wave = t >> 6;
  const int rb = (wave >> 1) * 64 + (lane >> 4) * 4;
  const int cb = (wave & 1) * 64 + (lane & 15);
  const float* lrow = lsum + (long)b * S;

#pragma unroll
  for (int i = 0; i < 4; ++i) {
#pragma unroll
    for (int r_ = 0; r_ < 4; ++r_) {
      const int row = mb * BM + rb + i * 16 + r_;
      const float inv = 1.f / lrow[row];
#pragma unroll
      for (int j4 = 0; j4 < 4; ++j4) {
        const int col = nb * 128 + cb + j4 * 16;
        out[((long)b * S + row) * D + col] = acc[i][j4][r_] * inv + bo[col];
      }
    }
  }
}

// ---------------- prep ------------------------------------------------------
// [0,8192): cast x | [8192,8448): Wq^T | [8448,8704): Wk^T | [8704,8960): Wv^T
// [8960,9984): cast Wo | [9984,11008): bvo | [11008]: zero lsum
__global__ void prep(const float* __restrict__ x, const float* __restrict__ Wq,
                     const float* __restrict__ Wk, const float* __restrict__ Wv,
                     const float* __restrict__ Wo, const float* __restrict__ bv,
                     __bf16* __restrict__ xb, __bf16* __restrict__ Wqt,
                     __bf16* __restrict__ Wkt, __bf16* __restrict__ Wvt,
                     __bf16* __restrict__ Wob, float* __restrict__ bvo,
                     float* __restrict__ lsum) {
  __shared__ __bf16 tile[64][66];
  __shared__ float wsum[4];
  const int bid = blockIdx.x;
  const int t = threadIdx.x;
  if (bid < 8192) {
    const long i = ((long)bid * 256 + t) * 4;
    const float4 f = *(const float4*)(x + i);
    bf16x4 o;
    o[0] = (__bf16)f.x; o[1] = (__bf16)f.y; o[2] = (__bf16)f.z; o[3] = (__bf16)f.w;
    *(bf16x4*)(xb + i) = o;
  } else if (bid < 8960) {
    // transpose-cast: dst[c][r] = (bf16)src[r][c], 256 64x64 tiles each
    const int which = (bid - 8192) >> 8;
    const int idx = (bid - 8192) & 255;
    const float* src = which == 0 ? Wq : (which == 1 ? Wk : Wv);
    __bf16* dst = which == 0 ? Wqt : (which == 1 ? Wkt : Wvt);
    const int r0 = (idx >> 4) * 64, c0 = (idx & 15) * 64;
#pragma unroll
    for (int e = 0; e < 16; ++e) {
      const int i = e * 256 + t;
      const int r = i >> 6, c = i & 63;
      tile[r][c] = (__bf16)src[(long)(r0 + r) * 1024 + (c0 + c)];
    }
    __syncthreads();
#pragma unroll
    for (int e = 0; e < 16; ++e) {
      const int i = e * 256 + t;
      const int r = i >> 6, c = i & 63;
      dst[(long)(c0 + r) * 1024 + (r0 + c)] = tile[c][r];
    }
  } else if (bid < 9984) {
    const long i = ((long)(bid - 8960) * 256 + t) * 4;
    const float4 f = *(const float4*)(Wo + i);
    bf16x4 o;
    o[0] = (__bf16)f.x; o[1] = (__bf16)f.y; o[2] = (__bf16)f.z; o[3] = (__bf16)f.w;
    *(bf16x4*)(Wob + i) = o;
  } else if (bid < 11008) {
    // bvo[d] = sum_v bv[v] * Wo[d][v]
    const int d = bid - 9984;
    const float* row = Wo + (long)d * 1024;
    float s = 0.f;
    for (int v = t; v < 1024; v += 256) s += bv[v] * row[v];
#pragma unroll
    for (int off = 32; off > 0; off >>= 1) s += __shfl_down(s, off, 64);
    if ((t & 63) == 0) wsum[t >> 6] = s;
    __syncthreads();
    if (t == 0) bvo[d] = wsum[0] + wsum[1] + wsum[2] + wsum[3];
  } else {
#pragma unroll
    for (int e = 0; e < 8; ++e)
      *(float4*)(lsum + (e * 256 + t) * 4) = float4{0.f, 0.f, 0.f, 0.f};
  }
}

extern "C" void kernel_launch(void* const* d_in, const int* in_sizes, int n_in,
                              void* d_out, int out_size, void* d_ws, size_t ws_size,
                              hipStream_t stream) {
  const float* x = (const float*)d_in[0];
  const float* Wq = (const float*)d_in[1];
  const float* bq = (const float*)d_in[2];
  const float* Wk = (const float*)d_in[3];
  const float* bk = (const float*)d_in[4];
  const float* Wv = (const float*)d_in[5];
  const float* bv = (const float*)d_in[6];
  const float* Wo = (const float*)d_in[7];
  const float* bo = (const float*)d_in[8];
  float* out = (float*)d_out;

  constexpr int B = 4, S = 2048, D = 1024;
  constexpr long MB_ = 1024 * 1024;

  char* w = (char*)d_ws;
  __bf16* xb  = (__bf16*)(w);              // 16 MB
  __bf16* yb  = (__bf16*)(w + 16 * MB_);   // 16 MB
  __bf16* Ut  = (__bf16*)(w + 32 * MB_);   // 16 MB
  __bf16* P   = (__bf16*)(w + 48 * MB_);   // 32 MB
  __bf16* Mqk = (__bf16*)(w + 80 * MB_);   // 2 MB
  __bf16* Wvo = (__bf16*)(w + 82 * MB_);   // 2 MB
  __bf16* Wqt = (__bf16*)(w + 84 * MB_);   // 2 MB
  __bf16* Wkt = (__bf16*)(w + 86 * MB_);   // 2 MB
  __bf16* Wvt = (__bf16*)(w + 88 * MB_);   // 2 MB
  __bf16* Wob = (__bf16*)(w + 90 * MB_);   // 2 MB
  float* lsum = (float*)(w + 92 * MB_);            // 32 KB
  float* r1   = (float*)(w + 92 * MB_ + 32768);    // 32 KB
  float* w1   = (float*)(w + 92 * MB_ + 65536);    // 4 KB
  float* w2   = (float*)(w + 92 * MB_ + 69632);    // 4 KB
  float* bvo  = (float*)(w + 92 * MB_ + 73728);    // 4 KB
  float* cbuf = (float*)(w + 92 * MB_ + 77824);    // 4 B

  prep<<<11009, 256, 0, stream>>>(x, Wq, Wk, Wv, Wo, bv, xb, Wqt, Wkt, Wvt,
                                  Wob, bvo, lsum);

  wcomb<<<145, 256, 0, stream>>>(Wqt, Wkt, Wob, Wvt, Mqk, Wvo, bq, bk, w1, w2,
                                 cbuf);

  proj<<<1088, 256, 0, stream>>>(xb, Mqk, Wvo, w2, bvo, w1, cbuf, yb, Ut, r1,
                                 S, D);

  gemm_scores<<<544, 256, 0, stream>>>(yb, xb, r1, P, lsum, S, D);

  gemm_pvo<<<512, 256, 0, stream>>>(P, Ut, lsum, bo, out, S, D);
}